// Round 8
// baseline (568.830 us; speedup 1.0000x reference)
//
#include <hip/hip_runtime.h>

#define N_NODES 100000
#define HID 256
#define N_EDGES 1500000
#define N_REL 3
#define E_PER_REL (N_EDGES / N_REL)
#define NKEYS (N_REL * N_NODES)
#define KP 640                 // proj K  (256 + 384)
#define KR 768                 // relation K (3 * 256)

#define SCAN_CHUNK 1024
#define NSCANBLK ((NKEYS + SCAN_CHUNK - 1) / SCAN_CHUNK)   // 293

typedef __attribute__((ext_vector_type(8))) short bf16x8;
typedef __attribute__((ext_vector_type(4))) float f32x4;

__device__ __forceinline__ short f2bf(float x) {  // RNE f32 -> bf16
    union { float f; unsigned u; } v; v.f = x;
    unsigned r = v.u + 0x7fffu + ((v.u >> 16) & 1u);
    return (short)(r >> 16);
}
__device__ __forceinline__ float bf2f(short h) {
    union { unsigned u; float f; } v;
    v.u = ((unsigned)(unsigned short)h) << 16;
    return v.f;
}
// slot swizzle: LDS row layout = [row][slot^xorf(row)], slot = 16B unit
__device__ __forceinline__ int xorf(int r) { return (r & 3) ^ ((r >> 2) & 3); }

// ---------------------------------------------------------------------------
// Weight prep: WTp[c][k] = bf16(0.5 * Wp[k][c])  (Wp = [Wa;Wb], k in [0,640))
//              WTr[c][k] = bf16(Wr[k>>8][k&255][c])          (k in [0,768))
// ---------------------------------------------------------------------------
__global__ __launch_bounds__(256) void wprep_kernel(
    const float* __restrict__ Wa, const float* __restrict__ Wb,
    const float* __restrict__ Wr,
    short* __restrict__ WTp, short* __restrict__ WTr)
{
    int idx = blockIdx.x * 256 + threadIdx.x;
    if (idx < 256 * KP) {
        int c = idx / KP, k = idx - c * KP;
        float v = (k < 256) ? Wa[k * HID + c] : Wb[(k - 256) * HID + c];
        WTp[idx] = f2bf(0.5f * v);
    } else {
        int j = idx - 256 * KP;
        if (j < 256 * KR) {
            int c = j / KR, k = j - c * KR;
            WTr[j] = f2bf(Wr[(k >> 8) * HID * HID + (k & 255) * HID + c]);
        }
    }
}

// ---------------------------------------------------------------------------
// proj GEMM: h0h[N,256] (bf16) = bf16( fa@(.5Wa) + fb@(.5Wb) ), row 0 zeroed.
// 512 threads, 8 waves (2 x 4), tile 128x256, wave tile 64x64, BK=32.
// 2-deep register prefetch: set consumed at step t reloads for step t+2, so
// the vmcnt wait at each LDS write has ~2 iterations of latency slack.
// ---------------------------------------------------------------------------
__global__ __launch_bounds__(512, 4) void proj_gemm(
    const float* __restrict__ fa, const float* __restrict__ fb,
    const short* __restrict__ WTp, short* __restrict__ h0h)
{
    __shared__ short smA[128 * 32];   // 8 KB
    __shared__ short smB[256 * 32];   // 16 KB
    const int tid = threadIdx.x;
    const int lane = tid & 63;
    const int w = tid >> 6;
    const int wr = w >> 2, wc = w & 3;
    const int brow = blockIdx.x * 128;

    f32x4 acc[4][4] = {};

    // A staging: thread t covers (row = t>>2, k-quad = t&3) -> 8 floats
    const int arow = tid >> 2;
    const int akq = tid & 3;
    int garow = brow + arow;
    if (garow >= N_NODES) garow = N_NODES - 1;
    const int aslot = akq ^ xorf(arow);
    // B staging: thread t covers (col = t>>1, k-half = t&1) -> 16 bf16
    const int bcol = tid >> 1;
    const int bkh = tid & 1;
    const int bs0 = (2 * bkh + 0) ^ xorf(bcol);
    const int bs1 = (2 * bkh + 1) ^ xorf(bcol);

    auto loadA = [&](int k0, f32x4& o0, f32x4& o1) {
        const float* asrc; int astr, kk;
        if (k0 < 256) { asrc = fa; astr = 256; kk = k0; }
        else          { asrc = fb; astr = 384; kk = k0 - 256; }
        const float* ap = asrc + (size_t)garow * astr + kk + akq * 8;
        o0 = *(const f32x4*)(ap + 0);
        o1 = *(const f32x4*)(ap + 4);
    };
    auto loadB = [&](int k0, bf16x8& o0, bf16x8& o1) {
        const short* bp = WTp + (size_t)bcol * KP + k0 + bkh * 16;
        o0 = *(const bf16x8*)(bp + 0);
        o1 = *(const bf16x8*)(bp + 8);
    };

#define PROJ_STEP(pa0_, pa1_, pb0_, pb1_, nextk)                              \
    {                                                                         \
        __syncthreads();                                                      \
        bf16x8 ha;                                                            \
        ha[0] = f2bf(pa0_.x); ha[1] = f2bf(pa0_.y);                           \
        ha[2] = f2bf(pa0_.z); ha[3] = f2bf(pa0_.w);                           \
        ha[4] = f2bf(pa1_.x); ha[5] = f2bf(pa1_.y);                           \
        ha[6] = f2bf(pa1_.z); ha[7] = f2bf(pa1_.w);                           \
        *(bf16x8*)((char*)smA + arow * 64 + aslot * 16) = ha;                 \
        *(bf16x8*)((char*)smB + bcol * 64 + bs0 * 16) = pb0_;                 \
        *(bf16x8*)((char*)smB + bcol * 64 + bs1 * 16) = pb1_;                 \
        __syncthreads();                                                      \
        if ((nextk) < KP) { loadA((nextk), pa0_, pa1_);                       \
                            loadB((nextk), pb0_, pb1_); }                     \
        bf16x8 afr[4], bfr[4];                                                \
        _Pragma("unroll")                                                     \
        for (int m = 0; m < 4; ++m) {                                         \
            int rt = wr * 64 + m * 16 + (lane & 15);                          \
            int s = (lane >> 4) ^ xorf(rt);                                   \
            afr[m] = *(const bf16x8*)((const char*)smA + rt * 64 + s * 16);   \
        }                                                                     \
        _Pragma("unroll")                                                     \
        for (int n = 0; n < 4; ++n) {                                         \
            int ct = wc * 64 + n * 16 + (lane & 15);                          \
            int s = (lane >> 4) ^ xorf(ct);                                   \
            bfr[n] = *(const bf16x8*)((const char*)smB + ct * 64 + s * 16);   \
        }                                                                     \
        _Pragma("unroll")                                                     \
        for (int m = 0; m < 4; ++m)                                           \
            _Pragma("unroll")                                                 \
            for (int n = 0; n < 4; ++n)                                       \
                acc[m][n] = __builtin_amdgcn_mfma_f32_16x16x32_bf16(          \
                    afr[m], bfr[n], acc[m][n], 0, 0, 0);                      \
    }

    f32x4 paA0, paA1, paB0, paB1;
    bf16x8 pbA0, pbA1, pbB0, pbB1;
    loadA(0, paA0, paA1);  loadB(0, pbA0, pbA1);
    loadA(32, paB0, paB1); loadB(32, pbB0, pbB1);
    for (int k0 = 0; k0 < KP; k0 += 64) {
        PROJ_STEP(paA0, paA1, pbA0, pbA1, k0 + 64);
        PROJ_STEP(paB0, paB1, pbB0, pbB1, k0 + 96);
    }
#undef PROJ_STEP

    #pragma unroll
    for (int m = 0; m < 4; ++m) {
        #pragma unroll
        for (int j = 0; j < 4; ++j) {
            int row = brow + wr * 64 + m * 16 + ((lane >> 4) << 2) + j;
            if (row >= N_NODES) continue;
            #pragma unroll
            for (int n = 0; n < 4; ++n) {
                int col = wc * 64 + n * 16 + (lane & 15);
                short v = (row == 0) ? (short)0 : f2bf(acc[m][n][j]);
                h0h[(size_t)row * HID + col] = v;
            }
        }
    }
}

// ---------------------------------------------------------------------------
// rel GEMM + fused residual LayerNorm:
//   out[N,256] (f32) = LN( h0h + S@WTr^T ) * gamma + beta, row 0 zeroed.
// Same 2-deep prefetch structure.
// ---------------------------------------------------------------------------
__global__ __launch_bounds__(512, 4) void rel_gemm_ln(
    const short* __restrict__ S, const short* __restrict__ WTr,
    const short* __restrict__ h0h,
    const float* __restrict__ gamma, const float* __restrict__ beta,
    float* __restrict__ out)
{
    __shared__ short smA[128 * 32];     // 8 KB
    __shared__ short smB[256 * 32];     // 16 KB
    __shared__ float redS[128][4];      // 2 KB
    __shared__ float redS2[128][4];     // 2 KB
    __shared__ float smMean[128], smRs[128];   // 1 KB
    __shared__ float smG[256], smBt[256];      // 2 KB
    const int tid = threadIdx.x;
    const int lane = tid & 63;
    const int w = tid >> 6;
    const int wr = w >> 2, wc = w & 3;
    const int brow = blockIdx.x * 128;

    if (tid < 256) { smG[tid] = gamma[tid]; smBt[tid] = beta[tid]; }

    f32x4 acc[4][4] = {};

    const int arow = tid >> 2;
    const int akq = tid & 3;
    int garow = brow + arow;
    if (garow >= N_NODES) garow = N_NODES - 1;
    const int aslot = akq ^ xorf(arow);
    const int bcol = tid >> 1;
    const int bkh = tid & 1;
    const int bs0 = (2 * bkh + 0) ^ xorf(bcol);
    const int bs1 = (2 * bkh + 1) ^ xorf(bcol);

    auto loadA = [&](int k0, bf16x8& o) {
        o = *(const bf16x8*)(S + (size_t)garow * KR + k0 + akq * 8);
    };
    auto loadB = [&](int k0, bf16x8& o0, bf16x8& o1) {
        const short* bp = WTr + (size_t)bcol * KR + k0 + bkh * 16;
        o0 = *(const bf16x8*)(bp + 0);
        o1 = *(const bf16x8*)(bp + 8);
    };

#define REL_STEP(pa_, pb0_, pb1_, nextk)                                      \
    {                                                                         \
        __syncthreads();                                                      \
        *(bf16x8*)((char*)smA + arow * 64 + aslot * 16) = pa_;                \
        *(bf16x8*)((char*)smB + bcol * 64 + bs0 * 16) = pb0_;                 \
        *(bf16x8*)((char*)smB + bcol * 64 + bs1 * 16) = pb1_;                 \
        __syncthreads();                                                      \
        if ((nextk) < KR) { loadA((nextk), pa_);                              \
                            loadB((nextk), pb0_, pb1_); }                     \
        bf16x8 afr[4], bfr[4];                                                \
        _Pragma("unroll")                                                     \
        for (int m = 0; m < 4; ++m) {                                         \
            int rt = wr * 64 + m * 16 + (lane & 15);                          \
            int s = (lane >> 4) ^ xorf(rt);                                   \
            afr[m] = *(const bf16x8*)((const char*)smA + rt * 64 + s * 16);   \
        }                                                                     \
        _Pragma("unroll")                                                     \
        for (int n = 0; n < 4; ++n) {                                         \
            int ct = wc * 64 + n * 16 + (lane & 15);                          \
            int s = (lane >> 4) ^ xorf(ct);                                   \
            bfr[n] = *(const bf16x8*)((const char*)smB + ct * 64 + s * 16);   \
        }                                                                     \
        _Pragma("unroll")                                                     \
        for (int m = 0; m < 4; ++m)                                           \
            _Pragma("unroll")                                                 \
            for (int n = 0; n < 4; ++n)                                       \
                acc[m][n] = __builtin_amdgcn_mfma_f32_16x16x32_bf16(          \
                    afr[m], bfr[n], acc[m][n], 0, 0, 0);                      \
    }

    bf16x8 paA, paB, pbA0, pbA1, pbB0, pbB1;
    loadA(0, paA);  loadB(0, pbA0, pbA1);
    loadA(32, paB); loadB(32, pbB0, pbB1);
    for (int k0 = 0; k0 < KR; k0 += 64) {
        REL_STEP(paA, pbA0, pbA1, k0 + 64);
        REL_STEP(paB, pbB0, pbB1, k0 + 96);
    }
#undef REL_STEP

    // ---- epilogue: x = acc + h0 ; per-row mean/var ; LN ; write out ----
    #pragma unroll
    for (int m = 0; m < 4; ++m) {
        #pragma unroll
        for (int j = 0; j < 4; ++j) {
            int lrow = wr * 64 + m * 16 + ((lane >> 4) << 2) + j;
            int grow = brow + lrow;
            int crow = (grow < N_NODES) ? grow : 0;
            float s = 0.f, s2 = 0.f;
            #pragma unroll
            for (int n = 0; n < 4; ++n) {
                int col = wc * 64 + n * 16 + (lane & 15);
                float x = acc[m][n][j] + bf2f(h0h[(size_t)crow * HID + col]);
                acc[m][n][j] = x;
                s += x; s2 = fmaf(x, x, s2);
            }
            #pragma unroll
            for (int off = 1; off < 16; off <<= 1) {
                s += __shfl_xor(s, off, 64);
                s2 += __shfl_xor(s2, off, 64);
            }
            if ((lane & 15) == 0) { redS[lrow][wc] = s; redS2[lrow][wc] = s2; }
        }
    }
    __syncthreads();
    if (tid < 128) {
        float tot  = redS[tid][0] + redS[tid][1] + redS[tid][2] + redS[tid][3];
        float tot2 = redS2[tid][0] + redS2[tid][1] + redS2[tid][2] + redS2[tid][3];
        float mean = tot * (1.0f / HID);
        float var = tot2 * (1.0f / HID) - mean * mean;
        smMean[tid] = mean;
        smRs[tid] = rsqrtf(var + 1e-5f);
    }
    __syncthreads();
    #pragma unroll
    for (int m = 0; m < 4; ++m) {
        #pragma unroll
        for (int j = 0; j < 4; ++j) {
            int lrow = wr * 64 + m * 16 + ((lane >> 4) << 2) + j;
            int grow = brow + lrow;
            if (grow >= N_NODES) continue;
            float mean = smMean[lrow], rs = smRs[lrow];
            #pragma unroll
            for (int n = 0; n < 4; ++n) {
                int col = wc * 64 + n * 16 + (lane & 15);
                float y = (acc[m][n][j] - mean) * rs * smG[col] + smBt[col];
                out[(size_t)grow * HID + col] = (grow == 0) ? 0.f : y;
            }
        }
    }
}

// ---------------------------------------------------------------------------
// CSR build: histogram -> hierarchical exclusive scan -> bucket fill
// ---------------------------------------------------------------------------
__global__ __launch_bounds__(256) void hist_kernel(
    const int* __restrict__ dst, int* __restrict__ count)
{
    int i = blockIdx.x * 256 + threadIdx.x;
    if (i >= N_EDGES) return;
    int r = i / E_PER_REL;
    atomicAdd(&count[r * N_NODES + dst[i]], 1);
}

__global__ __launch_bounds__(256) void scan1_kernel(
    const int* __restrict__ count, int* __restrict__ offset,
    int* __restrict__ bsum)
{
    __shared__ int tmp[256];
    const int t = threadIdx.x;
    const int base = blockIdx.x * SCAN_CHUNK + t * 4;
    int v[4];
    #pragma unroll
    for (int j = 0; j < 4; ++j)
        v[j] = (base + j < NKEYS) ? count[base + j] : 0;
    int tsum = v[0] + v[1] + v[2] + v[3];
    tmp[t] = tsum;
    __syncthreads();
    #pragma unroll
    for (int off = 1; off < 256; off <<= 1) {
        int x = (t >= off) ? tmp[t - off] : 0;
        __syncthreads();
        tmp[t] += x;
        __syncthreads();
    }
    int run = tmp[t] - tsum;
    #pragma unroll
    for (int j = 0; j < 4; ++j) {
        if (base + j < NKEYS) offset[base + j] = run;
        run += v[j];
    }
    if (t == 0) bsum[blockIdx.x] = tmp[255];
}

__global__ __launch_bounds__(256) void scan2_kernel(int* __restrict__ bsum)
{
    __shared__ int tmp[256];
    const int t = threadIdx.x;
    int v0 = (2 * t     < NSCANBLK) ? bsum[2 * t]     : 0;
    int v1 = (2 * t + 1 < NSCANBLK) ? bsum[2 * t + 1] : 0;
    int psum = v0 + v1;
    tmp[t] = psum;
    __syncthreads();
    #pragma unroll
    for (int off = 1; off < 256; off <<= 1) {
        int x = (t >= off) ? tmp[t - off] : 0;
        __syncthreads();
        tmp[t] += x;
        __syncthreads();
    }
    int excl = tmp[t] - psum;
    if (2 * t     < NSCANBLK) bsum[2 * t]     = excl;
    if (2 * t + 1 < NSCANBLK) bsum[2 * t + 1] = excl + v0;
}

__global__ __launch_bounds__(256) void scan3_kernel(
    int* __restrict__ offset, const int* __restrict__ bsum)
{
    int i = blockIdx.x * 256 + threadIdx.x;
    if (i >= NKEYS) return;
    offset[i] += bsum[i / SCAN_CHUNK];
}

__global__ __launch_bounds__(256) void fill_kernel(
    const int* __restrict__ src, const int* __restrict__ dst,
    const float* __restrict__ w,
    int* __restrict__ offset, int* __restrict__ csr_src,
    float* __restrict__ csr_w)
{
    int i = blockIdx.x * 256 + threadIdx.x;
    if (i >= N_EDGES) return;
    int r = i / E_PER_REL;
    int key = r * N_NODES + dst[i];
    int pos = atomicAdd(&offset[key], 1);
    csr_src[pos] = src[i];
    csr_w[pos] = w[i];
}

// ---------------------------------------------------------------------------
// Gather: one wave per (relation, node).
// Lanes 0..deg-1 pre-load (src,w); loop shfl-broadcasts and issues 4
// independent row loads per chunk (tail predicated with w=0, dummy row =
// first edge's row -> cache hit). Serial fallback only for deg>64.
// ---------------------------------------------------------------------------
__global__ __launch_bounds__(256) void gather_kernel(
    const short* __restrict__ h0h,
    const int* __restrict__ ends, const int* __restrict__ count,
    const int* __restrict__ csr_src, const float* __restrict__ csr_w,
    short* __restrict__ S)
{
    int gw = (blockIdx.x * 256 + threadIdx.x) >> 6;
    int lane = threadIdx.x & 63;
    if (gw >= N_REL * N_NODES) return;
    int r = gw / N_NODES;
    int node = gw - r * N_NODES;
    int deg = count[gw];
    int end = ends[gw];
    int start = end - deg;
    const size_t colo = (size_t)lane * 4;

    float a0 = 0.f, a1 = 0.f, a2 = 0.f, a3 = 0.f;
    float den = 0.f;

    if (deg > 0) {
        int degc = (deg < 64) ? deg : 64;
        int myp = start + ((lane < degc) ? lane : 0);
        int msrc = csr_src[myp];
        float mw = (lane < degc) ? csr_w[myp] : 0.f;

        for (int p = 0; p < degc; p += 4) {
            #pragma unroll
            for (int j = 0; j < 4; ++j) {
                int q = p + j;
                bool ok = q < degc;
                int sj = __shfl(msrc, ok ? q : 0, 64);
                float wj = ok ? __shfl(mw, q, 64) : 0.f;
                short4 v = *(const short4*)(h0h + (size_t)sj * HID + colo);
                a0 = fmaf(wj, bf2f(v.x), a0);
                a1 = fmaf(wj, bf2f(v.y), a1);
                a2 = fmaf(wj, bf2f(v.z), a2);
                a3 = fmaf(wj, bf2f(v.w), a3);
                den += wj;
            }
        }
        // rare fallback for deg > 64
        for (int p = start + 64; p < end; ++p) {
            int s = csr_src[p];
            float wt = csr_w[p];
            short4 v = *(const short4*)(h0h + (size_t)s * HID + colo);
            a0 = fmaf(wt, bf2f(v.x), a0);
            a1 = fmaf(wt, bf2f(v.y), a1);
            a2 = fmaf(wt, bf2f(v.z), a2);
            a3 = fmaf(wt, bf2f(v.w), a3);
            den += wt;
        }
    }

    float inv = 1.0f / fmaxf(den, 1e-8f);
    short4 o;
    o.x = f2bf(a0 * inv);
    o.y = f2bf(a1 * inv);
    o.z = f2bf(a2 * inv);
    o.w = f2bf(a3 * inv);
    *(short4*)(S + (size_t)node * KR + r * HID + colo) = o;
}

// ---------------------------------------------------------------------------
extern "C" void kernel_launch(void* const* d_in, const int* in_sizes, int n_in,
                              void* d_out, int out_size, void* d_ws, size_t ws_size,
                              hipStream_t stream) {
    const float* fa    = (const float*)d_in[0];
    const float* fb    = (const float*)d_in[1];
    const float* Wa    = (const float*)d_in[2];
    const float* Wb    = (const float*)d_in[3];
    const float* Wr    = (const float*)d_in[4];
    const float* gamma = (const float*)d_in[5];
    const float* beta  = (const float*)d_in[6];
    const float* ew    = (const float*)d_in[7];
    const int*   esrc  = (const int*)d_in[8];
    const int*   edst  = (const int*)d_in[9];
    float* out = (float*)d_out;

    char* ws = (char*)d_ws;
    size_t off = 0;
    short* h0h     = (short*)(ws + off); off += (size_t)N_NODES * HID * 2;   // 51.2 MB
    short* S       = (short*)(ws + off); off += (size_t)N_NODES * KR * 2;    // 153.6 MB
    short* WTp     = (short*)(ws + off); off += (size_t)256 * KP * 2;
    short* WTr     = (short*)(ws + off); off += (size_t)256 * KR * 2;
    int*   count   = (int*)  (ws + off); off += (size_t)NKEYS * 4;
    int*   offs    = (int*)  (ws + off); off += (size_t)NKEYS * 4;
    int*   bsum    = (int*)  (ws + off); off += 4096;
    int*   csr_src = (int*)  (ws + off); off += (size_t)N_EDGES * 4;
    float* csr_w   = (float*)(ws + off); off += (size_t)N_EDGES * 4;

    wprep_kernel<<<(256 * KP + 256 * KR) / 256, 256, 0, stream>>>(
        Wa, Wb, Wr, WTp, WTr);

    const int ngrid = (N_NODES + 127) / 128;   // 782
    proj_gemm<<<ngrid, 512, 0, stream>>>(fa, fb, WTp, h0h);

    // CSR build
    hipMemsetAsync(count, 0, (size_t)NKEYS * 4, stream);
    const int egrid = (N_EDGES + 255) / 256;
    hist_kernel<<<egrid, 256, 0, stream>>>(edst, count);
    scan1_kernel<<<NSCANBLK, 256, 0, stream>>>(count, offs, bsum);
    scan2_kernel<<<1, 256, 0, stream>>>(bsum);
    scan3_kernel<<<(NKEYS + 255) / 256, 256, 0, stream>>>(offs, bsum);
    fill_kernel<<<egrid, 256, 0, stream>>>(esrc, edst, ew, offs, csr_src, csr_w);

    gather_kernel<<<(N_REL * N_NODES * 64) / 256, 256, 0, stream>>>(
        h0h, offs, count, csr_src, csr_w, S);

    rel_gemm_ln<<<ngrid, 512, 0, stream>>>(S, WTr, h0h, gamma, beta, out);
}

// Round 9
// 527.674 us; speedup vs baseline: 1.0780x; 1.0780x over previous
//
#include <hip/hip_runtime.h>

#define N_NODES 100000
#define HID 256
#define N_EDGES 1500000
#define N_REL 3
#define E_PER_REL (N_EDGES / N_REL)
#define NKEYS (N_REL * N_NODES)
#define KP 640                 // proj K  (256 + 384)
#define KR 768                 // relation K (3 * 256)

#define SCAN_CHUNK 1024
#define NSCANBLK ((NKEYS + SCAN_CHUNK - 1) / SCAN_CHUNK)   // 293

typedef __attribute__((ext_vector_type(8))) short bf16x8;
typedef __attribute__((ext_vector_type(4))) float f32x4;

__device__ __forceinline__ short f2bf(float x) {  // RNE f32 -> bf16
    union { float f; unsigned u; } v; v.f = x;
    unsigned r = v.u + 0x7fffu + ((v.u >> 16) & 1u);
    return (short)(r >> 16);
}
__device__ __forceinline__ float bf2f(short h) {
    union { unsigned u; float f; } v;
    v.u = ((unsigned)(unsigned short)h) << 16;
    return v.f;
}
// 4-slot swizzle (bf16 rows of 4 x 16B): phys = slot ^ xorf(row)
__device__ __forceinline__ int xorf(int r) { return (r & 3) ^ ((r >> 2) & 3); }

// async global->LDS, 16B/lane; LDS dest = wave-uniform base + lane*16
__device__ __forceinline__ void gload16(const void* g, void* l) {
    typedef const __attribute__((address_space(1))) unsigned int gq;
    typedef __attribute__((address_space(3))) unsigned int lq;
    __builtin_amdgcn_global_load_lds((gq*)g, (lq*)l, 16, 0, 0);
}

// ---------------------------------------------------------------------------
// Weight prep: WTp[c][k] = bf16(0.5 * Wp[k][c])  (Wp = [Wa;Wb], k in [0,640))
//              WTr[c][k] = bf16(Wr[k>>8][k&255][c])          (k in [0,768))
// ---------------------------------------------------------------------------
__global__ __launch_bounds__(256) void wprep_kernel(
    const float* __restrict__ Wa, const float* __restrict__ Wb,
    const float* __restrict__ Wr,
    short* __restrict__ WTp, short* __restrict__ WTr)
{
    int idx = blockIdx.x * 256 + threadIdx.x;
    if (idx < 256 * KP) {
        int c = idx / KP, k = idx - c * KP;
        float v = (k < 256) ? Wa[k * HID + c] : Wb[(k - 256) * HID + c];
        WTp[idx] = f2bf(0.5f * v);
    } else {
        int j = idx - 256 * KP;
        if (j < 256 * KR) {
            int c = j / KR, k = j - c * KR;
            WTr[j] = f2bf(Wr[(k >> 8) * HID * HID + (k & 255) * HID + c]);
        }
    }
}

// ---------------------------------------------------------------------------
// proj GEMM: h0h[N,256] (bf16) = bf16( fa@(.5Wa) + fb@(.5Wb) ), row 0 zeroed.
// 512 threads, 8 waves (2 x 4), tile 128x256, wave tile 64x64, BK=32.
// Double-buffered LDS + global_load_lds DMA staging (zero staging VGPRs).
// LDS A: f32 [128 rows][8 slots x 16B], phys slot = logical ^ (row & 7)
// LDS B: bf16 [256 cols][4 slots x 16B], phys slot = logical ^ xorf(col)
// Source is pre-swizzled per-lane (rule: linear dest + inv-swz source + swz read).
// ---------------------------------------------------------------------------
__global__ __launch_bounds__(512, 4) void proj_gemm(
    const float* __restrict__ fa, const float* __restrict__ fb,
    const short* __restrict__ WTp, short* __restrict__ h0h)
{
    __shared__ float smA[2][128 * 32];   // 2 x 16 KB
    __shared__ short smB[2][256 * 32];   // 2 x 16 KB
    const int tid = threadIdx.x;
    const int lane = tid & 63;
    const int w = tid >> 6;
    const int wr = w >> 2, wc = w & 3;
    const int brow = blockIdx.x * 128;

    f32x4 acc[4][4] = {};

    // A staging: wave-issue i covers rows 8i..8i+7; lane -> (row8, slot)
    const int a_r8 = lane >> 3;                 // 0..7
    const int a_sl = (lane & 7) ^ a_r8;         // pre-swizzled source chunk (x4 f32)
    // B staging: wave-issue i covers cols 16i..16i+15; lane -> (c16, slot)
    const int b_c16 = lane >> 2;                // 0..15

    int aRowG[2], bColL[2], bSl[2];
    #pragma unroll
    for (int ii = 0; ii < 2; ++ii) {
        int i = w * 2 + ii;
        int gr = brow + i * 8 + a_r8;
        aRowG[ii] = (gr < N_NODES) ? gr : (N_NODES - 1);
        bColL[ii] = i * 16 + b_c16;
        bSl[ii] = (lane & 3) ^ xorf(bColL[ii]);
    }

    auto stage = [&](int buf, int k0) {
        const float* asrc; int astr, kk;
        if (k0 < 256) { asrc = fa; astr = 256; kk = k0; }
        else          { asrc = fb; astr = 384; kk = k0 - 256; }
        #pragma unroll
        for (int ii = 0; ii < 2; ++ii) {
            int i = w * 2 + ii;
            gload16(asrc + (size_t)aRowG[ii] * astr + kk + a_sl * 4,
                    (char*)&smA[buf][0] + i * 1024);
        }
        #pragma unroll
        for (int ii = 0; ii < 2; ++ii) {
            int i = w * 2 + ii;
            gload16(WTp + (size_t)bColL[ii] * KP + k0 + bSl[ii] * 8,
                    (char*)&smB[buf][0] + i * 1024);
        }
    };

    stage(0, 0);
    __syncthreads();   // implicit vmcnt(0) drain: buf0 ready
    int cur = 0;
    for (int t = 0; t < KP / 32; ++t) {
        int knext = (t + 1) * 32;
        if (knext < KP) stage(cur ^ 1, knext);   // async into other buffer

        bf16x8 afr[4], bfr[4];
        #pragma unroll
        for (int m = 0; m < 4; ++m) {
            int rt = wr * 64 + m * 16 + (lane & 15);
            int p0 = (((lane >> 4) << 1) | 0) ^ (rt & 7);
            int p1 = (((lane >> 4) << 1) | 1) ^ (rt & 7);
            f32x4 lo = *(const f32x4*)((const char*)&smA[cur][0] + rt * 128 + p0 * 16);
            f32x4 hi = *(const f32x4*)((const char*)&smA[cur][0] + rt * 128 + p1 * 16);
            bf16x8 tb;
            tb[0] = f2bf(lo.x); tb[1] = f2bf(lo.y); tb[2] = f2bf(lo.z); tb[3] = f2bf(lo.w);
            tb[4] = f2bf(hi.x); tb[5] = f2bf(hi.y); tb[6] = f2bf(hi.z); tb[7] = f2bf(hi.w);
            afr[m] = tb;
        }
        #pragma unroll
        for (int n = 0; n < 4; ++n) {
            int ct = wc * 64 + n * 16 + (lane & 15);
            int p = (lane >> 4) ^ xorf(ct);
            bfr[n] = *(const bf16x8*)((const char*)&smB[cur][0] + ct * 64 + p * 16);
        }
        #pragma unroll
        for (int m = 0; m < 4; ++m)
            #pragma unroll
            for (int n = 0; n < 4; ++n)
                acc[m][n] = __builtin_amdgcn_mfma_f32_16x16x32_bf16(
                    afr[m], bfr[n], acc[m][n], 0, 0, 0);

        __syncthreads();   // drains vmcnt (next tile landed) + all reads of cur done
        cur ^= 1;
    }

    #pragma unroll
    for (int m = 0; m < 4; ++m) {
        #pragma unroll
        for (int j = 0; j < 4; ++j) {
            int row = brow + wr * 64 + m * 16 + ((lane >> 4) << 2) + j;
            if (row >= N_NODES) continue;
            #pragma unroll
            for (int n = 0; n < 4; ++n) {
                int col = wc * 64 + n * 16 + (lane & 15);
                short v = (row == 0) ? (short)0 : f2bf(acc[m][n][j]);
                h0h[(size_t)row * HID + col] = v;
            }
        }
    }
}

// ---------------------------------------------------------------------------
// rel GEMM + fused residual LayerNorm:
//   out[N,256] (f32) = LN( h0h + S@WTr^T ) * gamma + beta, row 0 zeroed.
// Same double-buffered gload_lds structure; A (S) is bf16 4-slot rows.
// ---------------------------------------------------------------------------
__global__ __launch_bounds__(512, 4) void rel_gemm_ln(
    const short* __restrict__ S, const short* __restrict__ WTr,
    const short* __restrict__ h0h,
    const float* __restrict__ gamma, const float* __restrict__ beta,
    float* __restrict__ out)
{
    __shared__ short smA[2][128 * 32];   // 2 x 8 KB
    __shared__ short smB[2][256 * 32];   // 2 x 16 KB
    __shared__ float redS[128][4];       // 2 KB
    __shared__ float redS2[128][4];      // 2 KB
    __shared__ float smMean[128], smRs[128];   // 1 KB
    __shared__ float smG[256], smBt[256];      // 2 KB
    const int tid = threadIdx.x;
    const int lane = tid & 63;
    const int w = tid >> 6;
    const int wr = w >> 2, wc = w & 3;
    const int brow = blockIdx.x * 128;

    if (tid < 256) { smG[tid] = gamma[tid]; smBt[tid] = beta[tid]; }

    f32x4 acc[4][4] = {};

    // A staging: wave w's single issue covers rows 16w..16w+15
    const int s_r16 = lane >> 2;                // 0..15
    const int sRowL = w * 16 + s_r16;
    int gr0 = brow + sRowL;
    const int sRowG = (gr0 < N_NODES) ? gr0 : (N_NODES - 1);
    const int sSl = (lane & 3) ^ xorf(sRowL);
    // B staging: wave-issue i covers cols 16i..16i+15
    const int b_c16 = lane >> 2;
    int bColL[2], bSl[2];
    #pragma unroll
    for (int ii = 0; ii < 2; ++ii) {
        int i = w * 2 + ii;
        bColL[ii] = i * 16 + b_c16;
        bSl[ii] = (lane & 3) ^ xorf(bColL[ii]);
    }

    auto stage = [&](int buf, int k0) {
        gload16(S + (size_t)sRowG * KR + k0 + sSl * 8,
                (char*)&smA[buf][0] + w * 1024);
        #pragma unroll
        for (int ii = 0; ii < 2; ++ii) {
            int i = w * 2 + ii;
            gload16(WTr + (size_t)bColL[ii] * KR + k0 + bSl[ii] * 8,
                    (char*)&smB[buf][0] + i * 1024);
        }
    };

    stage(0, 0);
    __syncthreads();
    int cur = 0;
    for (int t = 0; t < KR / 32; ++t) {
        int knext = (t + 1) * 32;
        if (knext < KR) stage(cur ^ 1, knext);

        bf16x8 afr[4], bfr[4];
        #pragma unroll
        for (int m = 0; m < 4; ++m) {
            int rt = wr * 64 + m * 16 + (lane & 15);
            int p = (lane >> 4) ^ xorf(rt);
            afr[m] = *(const bf16x8*)((const char*)&smA[cur][0] + rt * 64 + p * 16);
        }
        #pragma unroll
        for (int n = 0; n < 4; ++n) {
            int ct = wc * 64 + n * 16 + (lane & 15);
            int p = (lane >> 4) ^ xorf(ct);
            bfr[n] = *(const bf16x8*)((const char*)&smB[cur][0] + ct * 64 + p * 16);
        }
        #pragma unroll
        for (int m = 0; m < 4; ++m)
            #pragma unroll
            for (int n = 0; n < 4; ++n)
                acc[m][n] = __builtin_amdgcn_mfma_f32_16x16x32_bf16(
                    afr[m], bfr[n], acc[m][n], 0, 0, 0);

        __syncthreads();
        cur ^= 1;
    }

    // ---- epilogue: x = acc + h0 ; per-row mean/var ; LN ; write out ----
    #pragma unroll
    for (int m = 0; m < 4; ++m) {
        #pragma unroll
        for (int j = 0; j < 4; ++j) {
            int lrow = wr * 64 + m * 16 + ((lane >> 4) << 2) + j;
            int grow = brow + lrow;
            int crow = (grow < N_NODES) ? grow : 0;
            float s = 0.f, s2 = 0.f;
            #pragma unroll
            for (int n = 0; n < 4; ++n) {
                int col = wc * 64 + n * 16 + (lane & 15);
                float x = acc[m][n][j] + bf2f(h0h[(size_t)crow * HID + col]);
                acc[m][n][j] = x;
                s += x; s2 = fmaf(x, x, s2);
            }
            #pragma unroll
            for (int off = 1; off < 16; off <<= 1) {
                s += __shfl_xor(s, off, 64);
                s2 += __shfl_xor(s2, off, 64);
            }
            if ((lane & 15) == 0) { redS[lrow][wc] = s; redS2[lrow][wc] = s2; }
        }
    }
    __syncthreads();
    if (tid < 128) {
        float tot  = redS[tid][0] + redS[tid][1] + redS[tid][2] + redS[tid][3];
        float tot2 = redS2[tid][0] + redS2[tid][1] + redS2[tid][2] + redS2[tid][3];
        float mean = tot * (1.0f / HID);
        float var = tot2 * (1.0f / HID) - mean * mean;
        smMean[tid] = mean;
        smRs[tid] = rsqrtf(var + 1e-5f);
    }
    __syncthreads();
    #pragma unroll
    for (int m = 0; m < 4; ++m) {
        #pragma unroll
        for (int j = 0; j < 4; ++j) {
            int lrow = wr * 64 + m * 16 + ((lane >> 4) << 2) + j;
            int grow = brow + lrow;
            if (grow >= N_NODES) continue;
            float mean = smMean[lrow], rs = smRs[lrow];
            #pragma unroll
            for (int n = 0; n < 4; ++n) {
                int col = wc * 64 + n * 16 + (lane & 15);
                float y = (acc[m][n][j] - mean) * rs * smG[col] + smBt[col];
                out[(size_t)grow * HID + col] = (grow == 0) ? 0.f : y;
            }
        }
    }
}

// ---------------------------------------------------------------------------
// CSR build: histogram -> hierarchical exclusive scan -> bucket fill
// ---------------------------------------------------------------------------
__global__ __launch_bounds__(256) void hist_kernel(
    const int* __restrict__ dst, int* __restrict__ count)
{
    int i = blockIdx.x * 256 + threadIdx.x;
    if (i >= N_EDGES) return;
    int r = i / E_PER_REL;
    atomicAdd(&count[r * N_NODES + dst[i]], 1);
}

__global__ __launch_bounds__(256) void scan1_kernel(
    const int* __restrict__ count, int* __restrict__ offset,
    int* __restrict__ bsum)
{
    __shared__ int tmp[256];
    const int t = threadIdx.x;
    const int base = blockIdx.x * SCAN_CHUNK + t * 4;
    int v[4];
    #pragma unroll
    for (int j = 0; j < 4; ++j)
        v[j] = (base + j < NKEYS) ? count[base + j] : 0;
    int tsum = v[0] + v[1] + v[2] + v[3];
    tmp[t] = tsum;
    __syncthreads();
    #pragma unroll
    for (int off = 1; off < 256; off <<= 1) {
        int x = (t >= off) ? tmp[t - off] : 0;
        __syncthreads();
        tmp[t] += x;
        __syncthreads();
    }
    int run = tmp[t] - tsum;
    #pragma unroll
    for (int j = 0; j < 4; ++j) {
        if (base + j < NKEYS) offset[base + j] = run;
        run += v[j];
    }
    if (t == 0) bsum[blockIdx.x] = tmp[255];
}

__global__ __launch_bounds__(256) void scan2_kernel(int* __restrict__ bsum)
{
    __shared__ int tmp[256];
    const int t = threadIdx.x;
    int v0 = (2 * t     < NSCANBLK) ? bsum[2 * t]     : 0;
    int v1 = (2 * t + 1 < NSCANBLK) ? bsum[2 * t + 1] : 0;
    int psum = v0 + v1;
    tmp[t] = psum;
    __syncthreads();
    #pragma unroll
    for (int off = 1; off < 256; off <<= 1) {
        int x = (t >= off) ? tmp[t - off] : 0;
        __syncthreads();
        tmp[t] += x;
        __syncthreads();
    }
    int excl = tmp[t] - psum;
    if (2 * t     < NSCANBLK) bsum[2 * t]     = excl;
    if (2 * t + 1 < NSCANBLK) bsum[2 * t + 1] = excl + v0;
}

__global__ __launch_bounds__(256) void scan3_kernel(
    int* __restrict__ offset, const int* __restrict__ bsum)
{
    int i = blockIdx.x * 256 + threadIdx.x;
    if (i >= NKEYS) return;
    offset[i] += bsum[i / SCAN_CHUNK];
}

__global__ __launch_bounds__(256) void fill_kernel(
    const int* __restrict__ src, const int* __restrict__ dst,
    const float* __restrict__ w,
    int* __restrict__ offset, int* __restrict__ csr_src,
    float* __restrict__ csr_w)
{
    int i = blockIdx.x * 256 + threadIdx.x;
    if (i >= N_EDGES) return;
    int r = i / E_PER_REL;
    int key = r * N_NODES + dst[i];
    int pos = atomicAdd(&offset[key], 1);
    csr_src[pos] = src[i];
    csr_w[pos] = w[i];
}

// ---------------------------------------------------------------------------
// Gather: one wave per (relation, node). Lanes 0..deg-1 pre-load (src,w);
// loop shfl-broadcasts and issues 4 independent row loads per chunk.
// ---------------------------------------------------------------------------
__global__ __launch_bounds__(256) void gather_kernel(
    const short* __restrict__ h0h,
    const int* __restrict__ ends, const int* __restrict__ count,
    const int* __restrict__ csr_src, const float* __restrict__ csr_w,
    short* __restrict__ S)
{
    int gw = (blockIdx.x * 256 + threadIdx.x) >> 6;
    int lane = threadIdx.x & 63;
    if (gw >= N_REL * N_NODES) return;
    int r = gw / N_NODES;
    int node = gw - r * N_NODES;
    int deg = count[gw];
    int end = ends[gw];
    int start = end - deg;
    const size_t colo = (size_t)lane * 4;

    float a0 = 0.f, a1 = 0.f, a2 = 0.f, a3 = 0.f;
    float den = 0.f;

    if (deg > 0) {
        int degc = (deg < 64) ? deg : 64;
        int myp = start + ((lane < degc) ? lane : 0);
        int msrc = csr_src[myp];
        float mw = (lane < degc) ? csr_w[myp] : 0.f;

        for (int p = 0; p < degc; p += 4) {
            #pragma unroll
            for (int j = 0; j < 4; ++j) {
                int q = p + j;
                bool ok = q < degc;
                int sj = __shfl(msrc, ok ? q : 0, 64);
                float wj = ok ? __shfl(mw, q, 64) : 0.f;
                short4 v = *(const short4*)(h0h + (size_t)sj * HID + colo);
                a0 = fmaf(wj, bf2f(v.x), a0);
                a1 = fmaf(wj, bf2f(v.y), a1);
                a2 = fmaf(wj, bf2f(v.z), a2);
                a3 = fmaf(wj, bf2f(v.w), a3);
                den += wj;
            }
        }
        for (int p = start + 64; p < end; ++p) {   // rare deg>64 fallback
            int s = csr_src[p];
            float wt = csr_w[p];
            short4 v = *(const short4*)(h0h + (size_t)s * HID + colo);
            a0 = fmaf(wt, bf2f(v.x), a0);
            a1 = fmaf(wt, bf2f(v.y), a1);
            a2 = fmaf(wt, bf2f(v.z), a2);
            a3 = fmaf(wt, bf2f(v.w), a3);
            den += wt;
        }
    }

    float inv = 1.0f / fmaxf(den, 1e-8f);
    short4 o;
    o.x = f2bf(a0 * inv);
    o.y = f2bf(a1 * inv);
    o.z = f2bf(a2 * inv);
    o.w = f2bf(a3 * inv);
    *(short4*)(S + (size_t)node * KR + r * HID + colo) = o;
}

// ---------------------------------------------------------------------------
extern "C" void kernel_launch(void* const* d_in, const int* in_sizes, int n_in,
                              void* d_out, int out_size, void* d_ws, size_t ws_size,
                              hipStream_t stream) {
    const float* fa    = (const float*)d_in[0];
    const float* fb    = (const float*)d_in[1];
    const float* Wa    = (const float*)d_in[2];
    const float* Wb    = (const float*)d_in[3];
    const float* Wr    = (const float*)d_in[4];
    const float* gamma = (const float*)d_in[5];
    const float* beta  = (const float*)d_in[6];
    const float* ew    = (const float*)d_in[7];
    const int*   esrc  = (const int*)d_in[8];
    const int*   edst  = (const int*)d_in[9];
    float* out = (float*)d_out;

    char* ws = (char*)d_ws;
    size_t off = 0;
    short* h0h     = (short*)(ws + off); off += (size_t)N_NODES * HID * 2;   // 51.2 MB
    short* S       = (short*)(ws + off); off += (size_t)N_NODES * KR * 2;    // 153.6 MB
    short* WTp     = (short*)(ws + off); off += (size_t)256 * KP * 2;
    short* WTr     = (short*)(ws + off); off += (size_t)256 * KR * 2;
    int*   count   = (int*)  (ws + off); off += (size_t)NKEYS * 4;
    int*   offs    = (int*)  (ws + off); off += (size_t)NKEYS * 4;
    int*   bsum    = (int*)  (ws + off); off += 4096;
    int*   csr_src = (int*)  (ws + off); off += (size_t)N_EDGES * 4;
    float* csr_w   = (float*)(ws + off); off += (size_t)N_EDGES * 4;

    wprep_kernel<<<(256 * KP + 256 * KR) / 256, 256, 0, stream>>>(
        Wa, Wb, Wr, WTp, WTr);

    const int ngrid = (N_NODES + 127) / 128;   // 782
    proj_gemm<<<ngrid, 512, 0, stream>>>(fa, fb, WTp, h0h);

    // CSR build
    hipMemsetAsync(count, 0, (size_t)NKEYS * 4, stream);
    const int egrid = (N_EDGES + 255) / 256;
    hist_kernel<<<egrid, 256, 0, stream>>>(edst, count);
    scan1_kernel<<<NSCANBLK, 256, 0, stream>>>(count, offs, bsum);
    scan2_kernel<<<1, 256, 0, stream>>>(bsum);
    scan3_kernel<<<(NKEYS + 255) / 256, 256, 0, stream>>>(offs, bsum);
    fill_kernel<<<egrid, 256, 0, stream>>>(esrc, edst, ew, offs, csr_src, csr_w);

    gather_kernel<<<(N_REL * N_NODES * 64) / 256, 256, 0, stream>>>(
        h0h, offs, count, csr_src, csr_w, S);

    rel_gemm_ln<<<ngrid, 512, 0, stream>>>(S, WTr, h0h, gamma, beta, out);
}

// Round 10
// 521.208 us; speedup vs baseline: 1.0914x; 1.0124x over previous
//
#include <hip/hip_runtime.h>

#define N_NODES 100000
#define HID 256
#define N_EDGES 1500000
#define N_REL 3
#define E_PER_REL (N_EDGES / N_REL)
#define NKEYS (N_REL * N_NODES)
#define KP 640                 // proj K  (256 + 384)
#define KR 768                 // relation K (3 * 256)

#define SCAN_CHUNK 1024
#define NSCANBLK ((NKEYS + SCAN_CHUNK - 1) / SCAN_CHUNK)   // 293

typedef __attribute__((ext_vector_type(8))) short bf16x8;
typedef __attribute__((ext_vector_type(4))) float f32x4;

__device__ __forceinline__ short f2bf(float x) {  // RNE f32 -> bf16
    union { float f; unsigned u; } v; v.f = x;
    unsigned r = v.u + 0x7fffu + ((v.u >> 16) & 1u);
    return (short)(r >> 16);
}
__device__ __forceinline__ float bf2f(short h) {
    union { unsigned u; float f; } v;
    v.u = ((unsigned)(unsigned short)h) << 16;
    return v.f;
}
// 4-slot swizzle (bf16 rows of 4 x 16B): phys = slot ^ xorf(row)
__device__ __forceinline__ int xorf(int r) { return (r & 3) ^ ((r >> 2) & 3); }

// async global->LDS, 16B/lane; LDS dest = wave-uniform base + lane*16
__device__ __forceinline__ void gload16(const void* g, void* l) {
    typedef const __attribute__((address_space(1))) unsigned int gq;
    typedef __attribute__((address_space(3))) unsigned int lq;
    __builtin_amdgcn_global_load_lds((gq*)g, (lq*)l, 16, 0, 0);
}

// ---------------------------------------------------------------------------
// Weight prep: WTp[c][k] = bf16(0.5 * Wp[k][c])  (Wp = [Wa;Wb], k in [0,640))
//              WTr[c][k] = bf16(Wr[k>>8][k&255][c])          (k in [0,768))
// ---------------------------------------------------------------------------
__global__ __launch_bounds__(256) void wprep_kernel(
    const float* __restrict__ Wa, const float* __restrict__ Wb,
    const float* __restrict__ Wr,
    short* __restrict__ WTp, short* __restrict__ WTr)
{
    int idx = blockIdx.x * 256 + threadIdx.x;
    if (idx < 256 * KP) {
        int c = idx / KP, k = idx - c * KP;
        float v = (k < 256) ? Wa[k * HID + c] : Wb[(k - 256) * HID + c];
        WTp[idx] = f2bf(0.5f * v);
    } else {
        int j = idx - 256 * KP;
        if (j < 256 * KR) {
            int c = j / KR, k = j - c * KR;
            WTr[j] = f2bf(Wr[(k >> 8) * HID * HID + (k & 255) * HID + c]);
        }
    }
}

// ---------------------------------------------------------------------------
// proj GEMM: h0h[N,256] (bf16) = bf16( fa@(.5Wa) + fb@(.5Wb) ), row 0 zeroed.
// 512 threads, 8 waves (2 x 4), tile 128x256, wave tile 64x64, BK=32.
// A: reg-staged (f32 load -> cvt once -> ds_write bf16), 2 named reg sets.
// B: global_load_lds DMA. LDS 48 KB total -> 3 blocks/CU. 1 barrier/step.
// ---------------------------------------------------------------------------
__global__ __launch_bounds__(512, 8) void proj_gemm(
    const float* __restrict__ fa, const float* __restrict__ fb,
    const short* __restrict__ WTp, short* __restrict__ h0h)
{
    __shared__ alignas(16) char lds[49152];   // A: 2x8 KB, B: 2x16 KB
    const int tid = threadIdx.x;
    const int lane = tid & 63;
    const int w = tid >> 6;
    const int wr = w >> 2, wc = w & 3;
    const int brow = blockIdx.x * 128;

    auto smA = [&](int b) -> char* { return lds + b * 8192; };
    auto smB = [&](int b) -> char* { return lds + 16384 + b * 16384; };

    f32x4 acc[4][4] = {};

    // A role: thread t covers (row = t>>2, k-quarter = t&3) -> 8 f32 -> 8 bf16
    const int arow = tid >> 2;
    const int akq = tid & 3;
    int gr = brow + arow;
    const int garow = (gr < N_NODES) ? gr : (N_NODES - 1);
    const int aslot = akq ^ xorf(arow);
    // B role (DMA): wave-issue i covers cols 16i..15; per-lane source pre-swizzled
    const int b_c16 = lane >> 2;
    int bColL[2], bSl[2];
    #pragma unroll
    for (int ii = 0; ii < 2; ++ii) {
        int i = w * 2 + ii;
        bColL[ii] = i * 16 + b_c16;
        bSl[ii] = (lane & 3) ^ xorf(bColL[ii]);
    }

    auto loadA = [&](int k0, f32x4& o0, f32x4& o1) {
        const float* asrc; int astr, kk;
        if (k0 < 256) { asrc = fa; astr = 256; kk = k0; }
        else          { asrc = fb; astr = 384; kk = k0 - 256; }
        const float* ap = asrc + (size_t)garow * astr + kk + akq * 8;
        o0 = *(const f32x4*)(ap + 0);
        o1 = *(const f32x4*)(ap + 4);
    };
    auto writeA = [&](int buf, const f32x4& v0, const f32x4& v1) {
        bf16x8 ha;
        ha[0] = f2bf(v0.x); ha[1] = f2bf(v0.y); ha[2] = f2bf(v0.z); ha[3] = f2bf(v0.w);
        ha[4] = f2bf(v1.x); ha[5] = f2bf(v1.y); ha[6] = f2bf(v1.z); ha[7] = f2bf(v1.w);
        *(bf16x8*)(smA(buf) + arow * 64 + aslot * 16) = ha;
    };
    auto stageB = [&](int buf, int k0) {
        #pragma unroll
        for (int ii = 0; ii < 2; ++ii) {
            int i = w * 2 + ii;
            gload16(WTp + (size_t)bColL[ii] * KP + k0 + bSl[ii] * 8,
                    smB(buf) + i * 1024);
        }
    };
    auto compute = [&](int buf) {
        bf16x8 afr[4], bfr[4];
        #pragma unroll
        for (int m = 0; m < 4; ++m) {
            int rt = wr * 64 + m * 16 + (lane & 15);
            int p = (lane >> 4) ^ xorf(rt);
            afr[m] = *(const bf16x8*)(smA(buf) + rt * 64 + p * 16);
        }
        #pragma unroll
        for (int n = 0; n < 4; ++n) {
            int ct = wc * 64 + n * 16 + (lane & 15);
            int p = (lane >> 4) ^ xorf(ct);
            bfr[n] = *(const bf16x8*)(smB(buf) + ct * 64 + p * 16);
        }
        #pragma unroll
        for (int m = 0; m < 4; ++m)
            #pragma unroll
            for (int n = 0; n < 4; ++n)
                acc[m][n] = __builtin_amdgcn_mfma_f32_16x16x32_bf16(
                    afr[m], bfr[n], acc[m][n], 0, 0, 0);
    };

    const int nt = KP / 32;   // 20 (even)
    f32x4 p0, p1, q0, q1;     // two named A prefetch sets (no runtime indexing)
    loadA(0, p0, p1);
    stageB(0, 0);
    loadA(32, q0, q1);
    writeA(0, p0, p1);
    __syncthreads();          // buf0 ready (vmcnt+lgkm drained)

    for (int t = 0; t < nt; t += 2) {
        // even step: compute buf0; prepare buf1 with A(t+1) from Q
        writeA(1, q0, q1);
        stageB(1, (t + 1) * 32);
        if (t + 2 < nt) loadA((t + 2) * 32, p0, p1);
        compute(0);
        __syncthreads();
        // odd step: compute buf1; prepare buf0 with A(t+2) from P
        if (t + 2 < nt) {
            writeA(0, p0, p1);
            stageB(0, (t + 2) * 32);
            if (t + 3 < nt) loadA((t + 3) * 32, q0, q1);
        }
        compute(1);
        __syncthreads();
    }

    #pragma unroll
    for (int m = 0; m < 4; ++m) {
        #pragma unroll
        for (int j = 0; j < 4; ++j) {
            int row = brow + wr * 64 + m * 16 + ((lane >> 4) << 2) + j;
            if (row >= N_NODES) continue;
            #pragma unroll
            for (int n = 0; n < 4; ++n) {
                int col = wc * 64 + n * 16 + (lane & 15);
                short v = (row == 0) ? (short)0 : f2bf(acc[m][n][j]);
                h0h[(size_t)row * HID + col] = v;
            }
        }
    }
}

// ---------------------------------------------------------------------------
// rel GEMM + fused residual LayerNorm:
//   out[N,256] (f32) = LN( h0h + S@WTr^T ) * gamma + beta, row 0 zeroed.
// Pure-DMA double buffer; epilogue LDS overlays the GEMM buffers -> 48 KB.
// ---------------------------------------------------------------------------
__global__ __launch_bounds__(512, 8) void rel_gemm_ln(
    const short* __restrict__ S, const short* __restrict__ WTr,
    const short* __restrict__ h0h,
    const float* __restrict__ gamma, const float* __restrict__ beta,
    float* __restrict__ out)
{
    __shared__ alignas(16) char lds[49152];   // A: 2x8 KB, B: 2x16 KB
    const int tid = threadIdx.x;
    const int lane = tid & 63;
    const int w = tid >> 6;
    const int wr = w >> 2, wc = w & 3;
    const int brow = blockIdx.x * 128;

    auto smA = [&](int b) -> char* { return lds + b * 8192; };
    auto smB = [&](int b) -> char* { return lds + 16384 + b * 16384; };

    f32x4 acc[4][4] = {};

    // A staging (DMA): wave w covers rows 16w..16w+15
    const int s_r16 = lane >> 2;
    const int sRowL = w * 16 + s_r16;
    int gr0 = brow + sRowL;
    const int sRowG = (gr0 < N_NODES) ? gr0 : (N_NODES - 1);
    const int sSl = (lane & 3) ^ xorf(sRowL);
    // B staging (DMA)
    const int b_c16 = lane >> 2;
    int bColL[2], bSl[2];
    #pragma unroll
    for (int ii = 0; ii < 2; ++ii) {
        int i = w * 2 + ii;
        bColL[ii] = i * 16 + b_c16;
        bSl[ii] = (lane & 3) ^ xorf(bColL[ii]);
    }

    auto stage = [&](int buf, int k0) {
        gload16(S + (size_t)sRowG * KR + k0 + sSl * 8, smA(buf) + w * 1024);
        #pragma unroll
        for (int ii = 0; ii < 2; ++ii) {
            int i = w * 2 + ii;
            gload16(WTr + (size_t)bColL[ii] * KR + k0 + bSl[ii] * 8,
                    smB(buf) + i * 1024);
        }
    };

    stage(0, 0);
    __syncthreads();
    int cur = 0;
    for (int t = 0; t < KR / 32; ++t) {
        int knext = (t + 1) * 32;
        if (knext < KR) stage(cur ^ 1, knext);

        bf16x8 afr[4], bfr[4];
        #pragma unroll
        for (int m = 0; m < 4; ++m) {
            int rt = wr * 64 + m * 16 + (lane & 15);
            int p = (lane >> 4) ^ xorf(rt);
            afr[m] = *(const bf16x8*)(smA(cur) + rt * 64 + p * 16);
        }
        #pragma unroll
        for (int n = 0; n < 4; ++n) {
            int ct = wc * 64 + n * 16 + (lane & 15);
            int p = (lane >> 4) ^ xorf(ct);
            bfr[n] = *(const bf16x8*)(smB(cur) + ct * 64 + p * 16);
        }
        #pragma unroll
        for (int m = 0; m < 4; ++m)
            #pragma unroll
            for (int n = 0; n < 4; ++n)
                acc[m][n] = __builtin_amdgcn_mfma_f32_16x16x32_bf16(
                    afr[m], bfr[n], acc[m][n], 0, 0, 0);

        __syncthreads();
        cur ^= 1;
    }

    // ---- epilogue: overlay reduction arrays on the (now-dead) GEMM LDS ----
    float* redS  = (float*)lds;          // [128][4]
    float* redS2 = redS + 512;           // [128][4]
    float* smMean = redS2 + 512;         // [128]
    float* smRs   = smMean + 128;        // [128]

    // per-thread gamma/beta for its 4 columns (L2-broadcast reads)
    float gk[4], bk[4];
    #pragma unroll
    for (int n = 0; n < 4; ++n) {
        int col = wc * 64 + n * 16 + (lane & 15);
        gk[n] = gamma[col];
        bk[n] = beta[col];
    }

    #pragma unroll
    for (int m = 0; m < 4; ++m) {
        #pragma unroll
        for (int j = 0; j < 4; ++j) {
            int lrow = wr * 64 + m * 16 + ((lane >> 4) << 2) + j;
            int grow = brow + lrow;
            int crow = (grow < N_NODES) ? grow : 0;
            float s = 0.f, s2 = 0.f;
            #pragma unroll
            for (int n = 0; n < 4; ++n) {
                int col = wc * 64 + n * 16 + (lane & 15);
                float x = acc[m][n][j] + bf2f(h0h[(size_t)crow * HID + col]);
                acc[m][n][j] = x;
                s += x; s2 = fmaf(x, x, s2);
            }
            #pragma unroll
            for (int off = 1; off < 16; off <<= 1) {
                s += __shfl_xor(s, off, 64);
                s2 += __shfl_xor(s2, off, 64);
            }
            if ((lane & 15) == 0) { redS[lrow * 4 + wc] = s; redS2[lrow * 4 + wc] = s2; }
        }
    }
    __syncthreads();
    if (tid < 128) {
        float tot  = redS[tid * 4 + 0] + redS[tid * 4 + 1] + redS[tid * 4 + 2] + redS[tid * 4 + 3];
        float tot2 = redS2[tid * 4 + 0] + redS2[tid * 4 + 1] + redS2[tid * 4 + 2] + redS2[tid * 4 + 3];
        float mean = tot * (1.0f / HID);
        float var = tot2 * (1.0f / HID) - mean * mean;
        smMean[tid] = mean;
        smRs[tid] = rsqrtf(var + 1e-5f);
    }
    __syncthreads();
    #pragma unroll
    for (int m = 0; m < 4; ++m) {
        #pragma unroll
        for (int j = 0; j < 4; ++j) {
            int lrow = wr * 64 + m * 16 + ((lane >> 4) << 2) + j;
            int grow = brow + lrow;
            if (grow >= N_NODES) continue;
            float mean = smMean[lrow], rs = smRs[lrow];
            #pragma unroll
            for (int n = 0; n < 4; ++n) {
                int col = wc * 64 + n * 16 + (lane & 15);
                float y = (acc[m][n][j] - mean) * rs * gk[n] + bk[n];
                out[(size_t)grow * HID + col] = (grow == 0) ? 0.f : y;
            }
        }
    }
}

// ---------------------------------------------------------------------------
// CSR build: histogram -> hierarchical exclusive scan -> bucket fill
// ---------------------------------------------------------------------------
__global__ __launch_bounds__(256) void hist_kernel(
    const int* __restrict__ dst, int* __restrict__ count)
{
    int i = blockIdx.x * 256 + threadIdx.x;
    if (i >= N_EDGES) return;
    int r = i / E_PER_REL;
    atomicAdd(&count[r * N_NODES + dst[i]], 1);
}

__global__ __launch_bounds__(256) void scan1_kernel(
    const int* __restrict__ count, int* __restrict__ offset,
    int* __restrict__ bsum)
{
    __shared__ int tmp[256];
    const int t = threadIdx.x;
    const int base = blockIdx.x * SCAN_CHUNK + t * 4;
    int v[4];
    #pragma unroll
    for (int j = 0; j < 4; ++j)
        v[j] = (base + j < NKEYS) ? count[base + j] : 0;
    int tsum = v[0] + v[1] + v[2] + v[3];
    tmp[t] = tsum;
    __syncthreads();
    #pragma unroll
    for (int off = 1; off < 256; off <<= 1) {
        int x = (t >= off) ? tmp[t - off] : 0;
        __syncthreads();
        tmp[t] += x;
        __syncthreads();
    }
    int run = tmp[t] - tsum;
    #pragma unroll
    for (int j = 0; j < 4; ++j) {
        if (base + j < NKEYS) offset[base + j] = run;
        run += v[j];
    }
    if (t == 0) bsum[blockIdx.x] = tmp[255];
}

__global__ __launch_bounds__(256) void scan2_kernel(int* __restrict__ bsum)
{
    __shared__ int tmp[256];
    const int t = threadIdx.x;
    int v0 = (2 * t     < NSCANBLK) ? bsum[2 * t]     : 0;
    int v1 = (2 * t + 1 < NSCANBLK) ? bsum[2 * t + 1] : 0;
    int psum = v0 + v1;
    tmp[t] = psum;
    __syncthreads();
    #pragma unroll
    for (int off = 1; off < 256; off <<= 1) {
        int x = (t >= off) ? tmp[t - off] : 0;
        __syncthreads();
        tmp[t] += x;
        __syncthreads();
    }
    int excl = tmp[t] - psum;
    if (2 * t     < NSCANBLK) bsum[2 * t]     = excl;
    if (2 * t + 1 < NSCANBLK) bsum[2 * t + 1] = excl + v0;
}

__global__ __launch_bounds__(256) void scan3_kernel(
    int* __restrict__ offset, const int* __restrict__ bsum)
{
    int i = blockIdx.x * 256 + threadIdx.x;
    if (i >= NKEYS) return;
    offset[i] += bsum[i / SCAN_CHUNK];
}

__global__ __launch_bounds__(256) void fill_kernel(
    const int* __restrict__ src, const int* __restrict__ dst,
    const float* __restrict__ w,
    int* __restrict__ offset, int* __restrict__ csr_src,
    float* __restrict__ csr_w)
{
    int i = blockIdx.x * 256 + threadIdx.x;
    if (i >= N_EDGES) return;
    int r = i / E_PER_REL;
    int key = r * N_NODES + dst[i];
    int pos = atomicAdd(&offset[key], 1);
    csr_src[pos] = src[i];
    csr_w[pos] = w[i];
}

// ---------------------------------------------------------------------------
// Gather: one wave per (relation, node). Lanes 0..deg-1 pre-load (src,w);
// loop shfl-broadcasts and issues 4 independent row loads per chunk.
// ---------------------------------------------------------------------------
__global__ __launch_bounds__(256) void gather_kernel(
    const short* __restrict__ h0h,
    const int* __restrict__ ends, const int* __restrict__ count,
    const int* __restrict__ csr_src, const float* __restrict__ csr_w,
    short* __restrict__ S)
{
    int gw = (blockIdx.x * 256 + threadIdx.x) >> 6;
    int lane = threadIdx.x & 63;
    if (gw >= N_REL * N_NODES) return;
    int r = gw / N_NODES;
    int node = gw - r * N_NODES;
    int deg = count[gw];
    int end = ends[gw];
    int start = end - deg;
    const size_t colo = (size_t)lane * 4;

    float a0 = 0.f, a1 = 0.f, a2 = 0.f, a3 = 0.f;
    float den = 0.f;

    if (deg > 0) {
        int degc = (deg < 64) ? deg : 64;
        int myp = start + ((lane < degc) ? lane : 0);
        int msrc = csr_src[myp];
        float mw = (lane < degc) ? csr_w[myp] : 0.f;

        for (int p = 0; p < degc; p += 4) {
            #pragma unroll
            for (int j = 0; j < 4; ++j) {
                int q = p + j;
                bool ok = q < degc;
                int sj = __shfl(msrc, ok ? q : 0, 64);
                float wj = ok ? __shfl(mw, q, 64) : 0.f;
                short4 v = *(const short4*)(h0h + (size_t)sj * HID + colo);
                a0 = fmaf(wj, bf2f(v.x), a0);
                a1 = fmaf(wj, bf2f(v.y), a1);
                a2 = fmaf(wj, bf2f(v.z), a2);
                a3 = fmaf(wj, bf2f(v.w), a3);
                den += wj;
            }
        }
        for (int p = start + 64; p < end; ++p) {   // rare deg>64 fallback
            int s = csr_src[p];
            float wt = csr_w[p];
            short4 v = *(const short4*)(h0h + (size_t)s * HID + colo);
            a0 = fmaf(wt, bf2f(v.x), a0);
            a1 = fmaf(wt, bf2f(v.y), a1);
            a2 = fmaf(wt, bf2f(v.z), a2);
            a3 = fmaf(wt, bf2f(v.w), a3);
            den += wt;
        }
    }

    float inv = 1.0f / fmaxf(den, 1e-8f);
    short4 o;
    o.x = f2bf(a0 * inv);
    o.y = f2bf(a1 * inv);
    o.z = f2bf(a2 * inv);
    o.w = f2bf(a3 * inv);
    *(short4*)(S + (size_t)node * KR + r * HID + colo) = o;
}

// ---------------------------------------------------------------------------
extern "C" void kernel_launch(void* const* d_in, const int* in_sizes, int n_in,
                              void* d_out, int out_size, void* d_ws, size_t ws_size,
                              hipStream_t stream) {
    const float* fa    = (const float*)d_in[0];
    const float* fb    = (const float*)d_in[1];
    const float* Wa    = (const float*)d_in[2];
    const float* Wb    = (const float*)d_in[3];
    const float* Wr    = (const float*)d_in[4];
    const float* gamma = (const float*)d_in[5];
    const float* beta  = (const float*)d_in[6];
    const float* ew    = (const float*)d_in[7];
    const int*   esrc  = (const int*)d_in[8];
    const int*   edst  = (const int*)d_in[9];
    float* out = (float*)d_out;

    char* ws = (char*)d_ws;
    size_t off = 0;
    short* h0h     = (short*)(ws + off); off += (size_t)N_NODES * HID * 2;   // 51.2 MB
    short* S       = (short*)(ws + off); off += (size_t)N_NODES * KR * 2;    // 153.6 MB
    short* WTp     = (short*)(ws + off); off += (size_t)256 * KP * 2;
    short* WTr     = (short*)(ws + off); off += (size_t)256 * KR * 2;
    int*   count   = (int*)  (ws + off); off += (size_t)NKEYS * 4;
    int*   offs    = (int*)  (ws + off); off += (size_t)NKEYS * 4;
    int*   bsum    = (int*)  (ws + off); off += 4096;
    int*   csr_src = (int*)  (ws + off); off += (size_t)N_EDGES * 4;
    float* csr_w   = (float*)(ws + off); off += (size_t)N_EDGES * 4;

    wprep_kernel<<<(256 * KP + 256 * KR) / 256, 256, 0, stream>>>(
        Wa, Wb, Wr, WTp, WTr);

    const int ngrid = (N_NODES + 127) / 128;   // 782
    proj_gemm<<<ngrid, 512, 0, stream>>>(fa, fb, WTp, h0h);

    // CSR build
    hipMemsetAsync(count, 0, (size_t)NKEYS * 4, stream);
    const int egrid = (N_EDGES + 255) / 256;
    hist_kernel<<<egrid, 256, 0, stream>>>(edst, count);
    scan1_kernel<<<NSCANBLK, 256, 0, stream>>>(count, offs, bsum);
    scan2_kernel<<<1, 256, 0, stream>>>(bsum);
    scan3_kernel<<<(NKEYS + 255) / 256, 256, 0, stream>>>(offs, bsum);
    fill_kernel<<<egrid, 256, 0, stream>>>(esrc, edst, ew, offs, csr_src, csr_w);

    gather_kernel<<<(N_REL * N_NODES * 64) / 256, 256, 0, stream>>>(
        h0h, offs, count, csr_src, csr_w, S);

    rel_gemm_ln<<<ngrid, 512, 0, stream>>>(S, WTr, h0h, gamma, beta, out);
}

// Round 11
// 501.946 us; speedup vs baseline: 1.1332x; 1.0384x over previous
//
#include <hip/hip_runtime.h>

#define N_NODES 100000
#define HID 256
#define N_EDGES 1500000
#define N_REL 3
#define E_PER_REL (N_EDGES / N_REL)
#define NKEYS (N_REL * N_NODES)
#define KP 640                 // proj K  (256 + 384)
#define KR 768                 // relation K (3 * 256)

#define SCAN_CHUNK 1024
#define NSCANBLK ((NKEYS + SCAN_CHUNK - 1) / SCAN_CHUNK)   // 293

typedef __attribute__((ext_vector_type(8))) short bf16x8;
typedef __attribute__((ext_vector_type(4))) float f32x4;

__device__ __forceinline__ short f2bf(float x) {  // RNE f32 -> bf16
    union { float f; unsigned u; } v; v.f = x;
    unsigned r = v.u + 0x7fffu + ((v.u >> 16) & 1u);
    return (short)(r >> 16);
}
__device__ __forceinline__ float bf2f(short h) {
    union { unsigned u; float f; } v;
    v.u = ((unsigned)(unsigned short)h) << 16;
    return v.f;
}
// 4-slot swizzle (bf16 rows of 4 x 16B): phys = slot ^ xorf(row)
__device__ __forceinline__ int xorf(int r) { return (r & 3) ^ ((r >> 2) & 3); }

// async global->LDS, 16B/lane; LDS dest = wave-uniform base + lane*16
__device__ __forceinline__ void gload16(const void* g, void* l) {
    typedef const __attribute__((address_space(1))) unsigned int gq;
    typedef __attribute__((address_space(3))) unsigned int lq;
    __builtin_amdgcn_global_load_lds((gq*)g, (lq*)l, 16, 0, 0);
}

// ---------------------------------------------------------------------------
// Weight prep: WTp[c][k] = bf16(0.5 * Wp[k][c])  (Wp = [Wa;Wb], k in [0,640))
//              WTr[c][k] = bf16(Wr[k>>8][k&255][c])          (k in [0,768))
// ---------------------------------------------------------------------------
__global__ __launch_bounds__(256) void wprep_kernel(
    const float* __restrict__ Wa, const float* __restrict__ Wb,
    const float* __restrict__ Wr,
    short* __restrict__ WTp, short* __restrict__ WTr)
{
    int idx = blockIdx.x * 256 + threadIdx.x;
    if (idx < 256 * KP) {
        int c = idx / KP, k = idx - c * KP;
        float v = (k < 256) ? Wa[k * HID + c] : Wb[(k - 256) * HID + c];
        WTp[idx] = f2bf(0.5f * v);
    } else {
        int j = idx - 256 * KP;
        if (j < 256 * KR) {
            int c = j / KR, k = j - c * KR;
            WTr[j] = f2bf(Wr[(k >> 8) * HID * HID + (k & 255) * HID + c]);
        }
    }
}

// ---------------------------------------------------------------------------
// proj GEMM: h0h[N,256] (bf16) = bf16( fa@(.5Wa) + fb@(.5Wb) ), row 0 zeroed.
// 512 threads, 8 waves (2 x 4), tile 128x256, wave tile 64x64, BK=32.
// 3-buffer ring, pure-DMA staging, COUNTED vmcnt (never drain to 0 mid-loop):
//   prologue stages 0,1,2; step t: vmcnt(8)->bar->read+MFMA->lgkm0->bar->stage(t+3)
// A staged as f32 (cvt to bf16 after ds_read). LDS 96 KB -> 1 block/CU.
// ---------------------------------------------------------------------------
__global__ __launch_bounds__(512, 2) void proj_gemm(
    const float* __restrict__ fa, const float* __restrict__ fb,
    const short* __restrict__ WTp, short* __restrict__ h0h)
{
    __shared__ alignas(16) char lds[98304];   // 3 x (A 16K f32 + B 16K bf16)
    const int tid = threadIdx.x;
    const int lane = tid & 63;
    const int w = tid >> 6;
    const int wr = w >> 2, wc = w & 3;
    const int brow = blockIdx.x * 128;

    auto bufA = [&](int b) -> char* { return lds + b * 32768; };
    auto bufB = [&](int b) -> char* { return lds + b * 32768 + 16384; };

    f32x4 acc[4][4] = {};

    // A staging (DMA f32): wave-issue i covers rows 8i..8i+7
    const int a_r8 = lane >> 3;                 // 0..7
    const int a_sl = (lane & 7) ^ a_r8;         // pre-swizzled source chunk (4 f32)
    int aRowG[2];
    #pragma unroll
    for (int ii = 0; ii < 2; ++ii) {
        int i = w * 2 + ii;
        int gr = brow + i * 8 + a_r8;
        aRowG[ii] = (gr < N_NODES) ? gr : (N_NODES - 1);
    }
    // B staging (DMA bf16): wave-issue i covers cols 16i..16i+15
    const int b_c16 = lane >> 2;
    int bColL[2], bSl[2];
    #pragma unroll
    for (int ii = 0; ii < 2; ++ii) {
        int i = w * 2 + ii;
        bColL[ii] = i * 16 + b_c16;
        bSl[ii] = (lane & 3) ^ xorf(bColL[ii]);
    }

    auto stage = [&](int b, int k0) {   // 4 loads/wave
        const float* asrc; int astr, kk;
        if (k0 < 256) { asrc = fa; astr = 256; kk = k0; }
        else          { asrc = fb; astr = 384; kk = k0 - 256; }
        #pragma unroll
        for (int ii = 0; ii < 2; ++ii) {
            int i = w * 2 + ii;
            gload16(asrc + (size_t)aRowG[ii] * astr + kk + a_sl * 4,
                    bufA(b) + i * 1024);
        }
        #pragma unroll
        for (int ii = 0; ii < 2; ++ii) {
            int i = w * 2 + ii;
            gload16(WTp + (size_t)bColL[ii] * KP + k0 + bSl[ii] * 8,
                    bufB(b) + i * 1024);
        }
    };

    const int nt = KP / 32;   // 20
    stage(0, 0); stage(1, 32); stage(2, 64);
    int cur = 0;
    for (int t = 0; t < nt; ++t) {
        // wait for stage t only; leave stages t+1,t+2 (4 loads each) in flight
        if (t < nt - 2)       asm volatile("s_waitcnt vmcnt(8)" ::: "memory");
        else if (t == nt - 2) asm volatile("s_waitcnt vmcnt(4)" ::: "memory");
        else                  asm volatile("s_waitcnt vmcnt(0)" ::: "memory");
        __builtin_amdgcn_s_barrier();

        bf16x8 afr[4], bfr[4];
        #pragma unroll
        for (int m = 0; m < 4; ++m) {
            int rt = wr * 64 + m * 16 + (lane & 15);
            int p0 = (((lane >> 4) << 1) | 0) ^ (rt & 7);
            int p1 = (((lane >> 4) << 1) | 1) ^ (rt & 7);
            f32x4 lo = *(const f32x4*)(bufA(cur) + rt * 128 + p0 * 16);
            f32x4 hi = *(const f32x4*)(bufA(cur) + rt * 128 + p1 * 16);
            bf16x8 tb;
            tb[0] = f2bf(lo.x); tb[1] = f2bf(lo.y); tb[2] = f2bf(lo.z); tb[3] = f2bf(lo.w);
            tb[4] = f2bf(hi.x); tb[5] = f2bf(hi.y); tb[6] = f2bf(hi.z); tb[7] = f2bf(hi.w);
            afr[m] = tb;
        }
        #pragma unroll
        for (int n = 0; n < 4; ++n) {
            int ct = wc * 64 + n * 16 + (lane & 15);
            int p = (lane >> 4) ^ xorf(ct);
            bfr[n] = *(const bf16x8*)(bufB(cur) + ct * 64 + p * 16);
        }
        #pragma unroll
        for (int m = 0; m < 4; ++m)
            #pragma unroll
            for (int n = 0; n < 4; ++n)
                acc[m][n] = __builtin_amdgcn_mfma_f32_16x16x32_bf16(
                    afr[m], bfr[n], acc[m][n], 0, 0, 0);

        asm volatile("s_waitcnt lgkmcnt(0)" ::: "memory");
        __builtin_amdgcn_sched_barrier(0);
        __builtin_amdgcn_s_barrier();          // all waves done reading buf cur
        if (t + 3 < nt) stage(cur, (t + 3) * 32);
        cur = (cur == 2) ? 0 : cur + 1;
    }

    #pragma unroll
    for (int m = 0; m < 4; ++m) {
        #pragma unroll
        for (int j = 0; j < 4; ++j) {
            int row = brow + wr * 64 + m * 16 + ((lane >> 4) << 2) + j;
            if (row >= N_NODES) continue;
            #pragma unroll
            for (int n = 0; n < 4; ++n) {
                int col = wc * 64 + n * 16 + (lane & 15);
                short v = (row == 0) ? (short)0 : f2bf(acc[m][n][j]);
                h0h[(size_t)row * HID + col] = v;
            }
        }
    }
}

// ---------------------------------------------------------------------------
// rel GEMM + fused residual LayerNorm:
//   out[N,256] (f32) = LN( h0h + S@WTr^T ) * gamma + beta, row 0 zeroed.
// Same 3-ring counted-vmcnt structure (3 loads/wave/stage -> vmcnt 6/3/0).
// LDS 72 KB -> 2 blocks/CU; epilogue overlays ring buffers.
// ---------------------------------------------------------------------------
__global__ __launch_bounds__(512, 4) void rel_gemm_ln(
    const short* __restrict__ S, const short* __restrict__ WTr,
    const short* __restrict__ h0h,
    const float* __restrict__ gamma, const float* __restrict__ beta,
    float* __restrict__ out)
{
    __shared__ alignas(16) char lds[73728];   // 3 x (A 8K + B 16K)
    const int tid = threadIdx.x;
    const int lane = tid & 63;
    const int w = tid >> 6;
    const int wr = w >> 2, wc = w & 3;
    const int brow = blockIdx.x * 128;

    auto bufA = [&](int b) -> char* { return lds + b * 24576; };
    auto bufB = [&](int b) -> char* { return lds + b * 24576 + 8192; };

    f32x4 acc[4][4] = {};

    // A staging (DMA): wave w covers rows 16w..16w+15
    const int s_r16 = lane >> 2;
    const int sRowL = w * 16 + s_r16;
    int gr0 = brow + sRowL;
    const int sRowG = (gr0 < N_NODES) ? gr0 : (N_NODES - 1);
    const int sSl = (lane & 3) ^ xorf(sRowL);
    // B staging (DMA)
    const int b_c16 = lane >> 2;
    int bColL[2], bSl[2];
    #pragma unroll
    for (int ii = 0; ii < 2; ++ii) {
        int i = w * 2 + ii;
        bColL[ii] = i * 16 + b_c16;
        bSl[ii] = (lane & 3) ^ xorf(bColL[ii]);
    }

    auto stage = [&](int b, int k0) {   // 3 loads/wave
        gload16(S + (size_t)sRowG * KR + k0 + sSl * 8, bufA(b) + w * 1024);
        #pragma unroll
        for (int ii = 0; ii < 2; ++ii) {
            int i = w * 2 + ii;
            gload16(WTr + (size_t)bColL[ii] * KR + k0 + bSl[ii] * 8,
                    bufB(b) + i * 1024);
        }
    };

    const int nt = KR / 32;   // 24
    stage(0, 0); stage(1, 32); stage(2, 64);
    int cur = 0;
    for (int t = 0; t < nt; ++t) {
        if (t < nt - 2)       asm volatile("s_waitcnt vmcnt(6)" ::: "memory");
        else if (t == nt - 2) asm volatile("s_waitcnt vmcnt(3)" ::: "memory");
        else                  asm volatile("s_waitcnt vmcnt(0)" ::: "memory");
        __builtin_amdgcn_s_barrier();

        bf16x8 afr[4], bfr[4];
        #pragma unroll
        for (int m = 0; m < 4; ++m) {
            int rt = wr * 64 + m * 16 + (lane & 15);
            int p = (lane >> 4) ^ xorf(rt);
            afr[m] = *(const bf16x8*)(bufA(cur) + rt * 64 + p * 16);
        }
        #pragma unroll
        for (int n = 0; n < 4; ++n) {
            int ct = wc * 64 + n * 16 + (lane & 15);
            int p = (lane >> 4) ^ xorf(ct);
            bfr[n] = *(const bf16x8*)(bufB(cur) + ct * 64 + p * 16);
        }
        #pragma unroll
        for (int m = 0; m < 4; ++m)
            #pragma unroll
            for (int n = 0; n < 4; ++n)
                acc[m][n] = __builtin_amdgcn_mfma_f32_16x16x32_bf16(
                    afr[m], bfr[n], acc[m][n], 0, 0, 0);

        asm volatile("s_waitcnt lgkmcnt(0)" ::: "memory");
        __builtin_amdgcn_sched_barrier(0);
        __builtin_amdgcn_s_barrier();
        if (t + 3 < nt) stage(cur, (t + 3) * 32);
        cur = (cur == 2) ? 0 : cur + 1;
    }

    // ---- epilogue: overlay reduction arrays on the (now-dead) GEMM LDS ----
    float* redS  = (float*)lds;          // [128][4]
    float* redS2 = redS + 512;           // [128][4]
    float* smMean = redS2 + 512;         // [128]
    float* smRs   = smMean + 128;        // [128]

    float gk[4], bk[4];
    #pragma unroll
    for (int n = 0; n < 4; ++n) {
        int col = wc * 64 + n * 16 + (lane & 15);
        gk[n] = gamma[col];
        bk[n] = beta[col];
    }

    #pragma unroll
    for (int m = 0; m < 4; ++m) {
        #pragma unroll
        for (int j = 0; j < 4; ++j) {
            int lrow = wr * 64 + m * 16 + ((lane >> 4) << 2) + j;
            int grow = brow + lrow;
            int crow = (grow < N_NODES) ? grow : 0;
            float s = 0.f, s2 = 0.f;
            #pragma unroll
            for (int n = 0; n < 4; ++n) {
                int col = wc * 64 + n * 16 + (lane & 15);
                float x = acc[m][n][j] + bf2f(h0h[(size_t)crow * HID + col]);
                acc[m][n][j] = x;
                s += x; s2 = fmaf(x, x, s2);
            }
            #pragma unroll
            for (int off = 1; off < 16; off <<= 1) {
                s += __shfl_xor(s, off, 64);
                s2 += __shfl_xor(s2, off, 64);
            }
            if ((lane & 15) == 0) { redS[lrow * 4 + wc] = s; redS2[lrow * 4 + wc] = s2; }
        }
    }
    __syncthreads();
    if (tid < 128) {
        float tot  = redS[tid * 4 + 0] + redS[tid * 4 + 1] + redS[tid * 4 + 2] + redS[tid * 4 + 3];
        float tot2 = redS2[tid * 4 + 0] + redS2[tid * 4 + 1] + redS2[tid * 4 + 2] + redS2[tid * 4 + 3];
        float mean = tot * (1.0f / HID);
        float var = tot2 * (1.0f / HID) - mean * mean;
        smMean[tid] = mean;
        smRs[tid] = rsqrtf(var + 1e-5f);
    }
    __syncthreads();
    #pragma unroll
    for (int m = 0; m < 4; ++m) {
        #pragma unroll
        for (int j = 0; j < 4; ++j) {
            int lrow = wr * 64 + m * 16 + ((lane >> 4) << 2) + j;
            int grow = brow + lrow;
            if (grow >= N_NODES) continue;
            float mean = smMean[lrow], rs = smRs[lrow];
            #pragma unroll
            for (int n = 0; n < 4; ++n) {
                int col = wc * 64 + n * 16 + (lane & 15);
                float y = (acc[m][n][j] - mean) * rs * gk[n] + bk[n];
                out[(size_t)grow * HID + col] = (grow == 0) ? 0.f : y;
            }
        }
    }
}

// ---------------------------------------------------------------------------
// CSR build: histogram -> hierarchical exclusive scan -> bucket fill
// ---------------------------------------------------------------------------
__global__ __launch_bounds__(256) void hist_kernel(
    const int* __restrict__ dst, int* __restrict__ count)
{
    int i = blockIdx.x * 256 + threadIdx.x;
    if (i >= N_EDGES) return;
    int r = i / E_PER_REL;
    atomicAdd(&count[r * N_NODES + dst[i]], 1);
}

__global__ __launch_bounds__(256) void scan1_kernel(
    const int* __restrict__ count, int* __restrict__ offset,
    int* __restrict__ bsum)
{
    __shared__ int tmp[256];
    const int t = threadIdx.x;
    const int base = blockIdx.x * SCAN_CHUNK + t * 4;
    int v[4];
    #pragma unroll
    for (int j = 0; j < 4; ++j)
        v[j] = (base + j < NKEYS) ? count[base + j] : 0;
    int tsum = v[0] + v[1] + v[2] + v[3];
    tmp[t] = tsum;
    __syncthreads();
    #pragma unroll
    for (int off = 1; off < 256; off <<= 1) {
        int x = (t >= off) ? tmp[t - off] : 0;
        __syncthreads();
        tmp[t] += x;
        __syncthreads();
    }
    int run = tmp[t] - tsum;
    #pragma unroll
    for (int j = 0; j < 4; ++j) {
        if (base + j < NKEYS) offset[base + j] = run;
        run += v[j];
    }
    if (t == 0) bsum[blockIdx.x] = tmp[255];
}

__global__ __launch_bounds__(256) void scan2_kernel(int* __restrict__ bsum)
{
    __shared__ int tmp[256];
    const int t = threadIdx.x;
    int v0 = (2 * t     < NSCANBLK) ? bsum[2 * t]     : 0;
    int v1 = (2 * t + 1 < NSCANBLK) ? bsum[2 * t + 1] : 0;
    int psum = v0 + v1;
    tmp[t] = psum;
    __syncthreads();
    #pragma unroll
    for (int off = 1; off < 256; off <<= 1) {
        int x = (t >= off) ? tmp[t - off] : 0;
        __syncthreads();
        tmp[t] += x;
        __syncthreads();
    }
    int excl = tmp[t] - psum;
    if (2 * t     < NSCANBLK) bsum[2 * t]     = excl;
    if (2 * t + 1 < NSCANBLK) bsum[2 * t + 1] = excl + v0;
}

__global__ __launch_bounds__(256) void scan3_kernel(
    int* __restrict__ offset, const int* __restrict__ bsum)
{
    int i = blockIdx.x * 256 + threadIdx.x;
    if (i >= NKEYS) return;
    offset[i] += bsum[i / SCAN_CHUNK];
}

__global__ __launch_bounds__(256) void fill_kernel(
    const int* __restrict__ src, const int* __restrict__ dst,
    const float* __restrict__ w,
    int* __restrict__ offset, int* __restrict__ csr_src,
    float* __restrict__ csr_w)
{
    int i = blockIdx.x * 256 + threadIdx.x;
    if (i >= N_EDGES) return;
    int r = i / E_PER_REL;
    int key = r * N_NODES + dst[i];
    int pos = atomicAdd(&offset[key], 1);
    csr_src[pos] = src[i];
    csr_w[pos] = w[i];
}

// ---------------------------------------------------------------------------
// Gather: one wave per (relation, node). Lanes 0..deg-1 pre-load (src,w);
// loop shfl-broadcasts and issues 4 independent row loads per chunk.
// ---------------------------------------------------------------------------
__global__ __launch_bounds__(256) void gather_kernel(
    const short* __restrict__ h0h,
    const int* __restrict__ ends, const int* __restrict__ count,
    const int* __restrict__ csr_src, const float* __restrict__ csr_w,
    short* __restrict__ S)
{
    int gw = (blockIdx.x * 256 + threadIdx.x) >> 6;
    int lane = threadIdx.x & 63;
    if (gw >= N_REL * N_NODES) return;
    int r = gw / N_NODES;
    int node = gw - r * N_NODES;
    int deg = count[gw];
    int end = ends[gw];
    int start = end - deg;
    const size_t colo = (size_t)lane * 4;

    float a0 = 0.f, a1 = 0.f, a2 = 0.f, a3 = 0.f;
    float den = 0.f;

    if (deg > 0) {
        int degc = (deg < 64) ? deg : 64;
        int myp = start + ((lane < degc) ? lane : 0);
        int msrc = csr_src[myp];
        float mw = (lane < degc) ? csr_w[myp] : 0.f;

        for (int p = 0; p < degc; p += 4) {
            #pragma unroll
            for (int j = 0; j < 4; ++j) {
                int q = p + j;
                bool ok = q < degc;
                int sj = __shfl(msrc, ok ? q : 0, 64);
                float wj = ok ? __shfl(mw, q, 64) : 0.f;
                short4 v = *(const short4*)(h0h + (size_t)sj * HID + colo);
                a0 = fmaf(wj, bf2f(v.x), a0);
                a1 = fmaf(wj, bf2f(v.y), a1);
                a2 = fmaf(wj, bf2f(v.z), a2);
                a3 = fmaf(wj, bf2f(v.w), a3);
                den += wj;
            }
        }
        for (int p = start + 64; p < end; ++p) {   // rare deg>64 fallback
            int s = csr_src[p];
            float wt = csr_w[p];
            short4 v = *(const short4*)(h0h + (size_t)s * HID + colo);
            a0 = fmaf(wt, bf2f(v.x), a0);
            a1 = fmaf(wt, bf2f(v.y), a1);
            a2 = fmaf(wt, bf2f(v.z), a2);
            a3 = fmaf(wt, bf2f(v.w), a3);
            den += wt;
        }
    }

    float inv = 1.0f / fmaxf(den, 1e-8f);
    short4 o;
    o.x = f2bf(a0 * inv);
    o.y = f2bf(a1 * inv);
    o.z = f2bf(a2 * inv);
    o.w = f2bf(a3 * inv);
    *(short4*)(S + (size_t)node * KR + r * HID + colo) = o;
}

// ---------------------------------------------------------------------------
extern "C" void kernel_launch(void* const* d_in, const int* in_sizes, int n_in,
                              void* d_out, int out_size, void* d_ws, size_t ws_size,
                              hipStream_t stream) {
    const float* fa    = (const float*)d_in[0];
    const float* fb    = (const float*)d_in[1];
    const float* Wa    = (const float*)d_in[2];
    const float* Wb    = (const float*)d_in[3];
    const float* Wr    = (const float*)d_in[4];
    const float* gamma = (const float*)d_in[5];
    const float* beta  = (const float*)d_in[6];
    const float* ew    = (const float*)d_in[7];
    const int*   esrc  = (const int*)d_in[8];
    const int*   edst  = (const int*)d_in[9];
    float* out = (float*)d_out;

    char* ws = (char*)d_ws;
    size_t off = 0;
    short* h0h     = (short*)(ws + off); off += (size_t)N_NODES * HID * 2;   // 51.2 MB
    short* S       = (short*)(ws + off); off += (size_t)N_NODES * KR * 2;    // 153.6 MB
    short* WTp     = (short*)(ws + off); off += (size_t)256 * KP * 2;
    short* WTr     = (short*)(ws + off); off += (size_t)256 * KR * 2;
    int*   count   = (int*)  (ws + off); off += (size_t)NKEYS * 4;
    int*   offs    = (int*)  (ws + off); off += (size_t)NKEYS * 4;
    int*   bsum    = (int*)  (ws + off); off += 4096;
    int*   csr_src = (int*)  (ws + off); off += (size_t)N_EDGES * 4;
    float* csr_w   = (float*)(ws + off); off += (size_t)N_EDGES * 4;

    wprep_kernel<<<(256 * KP + 256 * KR) / 256, 256, 0, stream>>>(
        Wa, Wb, Wr, WTp, WTr);

    const int ngrid = (N_NODES + 127) / 128;   // 782
    proj_gemm<<<ngrid, 512, 0, stream>>>(fa, fb, WTp, h0h);

    // CSR build
    hipMemsetAsync(count, 0, (size_t)NKEYS * 4, stream);
    const int egrid = (N_EDGES + 255) / 256;
    hist_kernel<<<egrid, 256, 0, stream>>>(edst, count);
    scan1_kernel<<<NSCANBLK, 256, 0, stream>>>(count, offs, bsum);
    scan2_kernel<<<1, 256, 0, stream>>>(bsum);
    scan3_kernel<<<(NKEYS + 255) / 256, 256, 0, stream>>>(offs, bsum);
    fill_kernel<<<egrid, 256, 0, stream>>>(esrc, edst, ew, offs, csr_src, csr_w);

    gather_kernel<<<(N_REL * N_NODES * 64) / 256, 256, 0, stream>>>(
        h0h, offs, count, csr_src, csr_w, S);

    rel_gemm_ln<<<ngrid, 512, 0, stream>>>(S, WTr, h0h, gamma, beta, out);
}